// Round 1
// baseline (921.958 us; speedup 1.0000x reference)
//
#include <hip/hip_runtime.h>

#define N_NODES 50000
#define N_EDGES 800000
#define IN_F    128
#define OUT_F   64
#define N_HEADS 4
#define NEG_SLOPE 0.2f
#define EPS 1e-12f

// ---------------------------------------------------------------------------
// K1: h = x @ W  (per-node), fused el = h@a_l, er = h@a_r via wave reduction.
// Block = 256 threads = 4 nodes, one wave (64 lanes) per node, lane = out feat.
// W (128x64 f32 = 32KB) staged in LDS once per block.
// ---------------------------------------------------------------------------
__global__ __launch_bounds__(256) void k_h_el_er(
    const float* __restrict__ x, const float* __restrict__ W,
    const float* __restrict__ a_l, const float* __restrict__ a_r,
    float* __restrict__ h, float* __restrict__ el, float* __restrict__ er)
{
    __shared__ float Wl[IN_F][OUT_F];   // 32 KB
    __shared__ float xs[4][IN_F];       // 2 KB
    const int tid = threadIdx.x;
    const int node0 = blockIdx.x * 4;

    for (int i = tid; i < IN_F * OUT_F; i += 256)
        Wl[i / OUT_F][i % OUT_F] = W[i];
    for (int i = tid; i < 4 * IN_F; i += 256) {
        int n = node0 + i / IN_F;
        xs[i / IN_F][i % IN_F] = (n < N_NODES) ? x[(size_t)n * IN_F + (i % IN_F)] : 0.f;
    }
    __syncthreads();

    const int local = tid >> 6;   // node within block == wave id
    const int d     = tid & 63;   // output feature
    const int n     = node0 + local;

    float acc = 0.f;
    #pragma unroll
    for (int k = 0; k < IN_F; ++k)
        acc += xs[local][k] * Wl[k][d];

    if (n < N_NODES) h[(size_t)n * OUT_F + d] = acc;

    // el[n][hd] = sum_d h[n][d] * a_l[d][hd]   (a_l is [OUT_F, N_HEADS] row-major)
    #pragma unroll
    for (int hd = 0; hd < N_HEADS; ++hd) {
        float vl = acc * a_l[d * N_HEADS + hd];
        float vr = acc * a_r[d * N_HEADS + hd];
        #pragma unroll
        for (int off = 32; off > 0; off >>= 1) {
            vl += __shfl_down(vl, off);
            vr += __shfl_down(vr, off);
        }
        if (d == 0 && n < N_NODES) {
            el[n * N_HEADS + hd] = vl;
            er[n * N_HEADS + hd] = vr;
        }
    }
}

// ---------------------------------------------------------------------------
// K2: per-edge exp(leaky_relu(el[row]+er[col])) accumulated into denom[row][hd]
// ---------------------------------------------------------------------------
__global__ __launch_bounds__(256) void k_denom(
    const int* __restrict__ row, const int* __restrict__ col,
    const float* __restrict__ el, const float* __restrict__ er,
    float* __restrict__ denom)
{
    int e = blockIdx.x * 256 + threadIdx.x;
    if (e >= N_EDGES) return;
    int r = row[e], c = col[e];
    float4 elv = *reinterpret_cast<const float4*>(el + r * 4);
    float4 erv = *reinterpret_cast<const float4*>(er + c * 4);
    float s[4] = {elv.x + erv.x, elv.y + erv.y, elv.z + erv.z, elv.w + erv.w};
    #pragma unroll
    for (int hd = 0; hd < 4; ++hd) {
        float v = s[hd] > 0.f ? s[hd] : NEG_SLOPE * s[hd];
        atomicAdd(&denom[r * 4 + hd], expf(v));
    }
}

// ---------------------------------------------------------------------------
// K3: one wave per edge; lane d holds h[col][d]; atomic accumulate
// e_hd * h[col][d] into unnormalized out[row][hd*64 + d].
// ---------------------------------------------------------------------------
__global__ __launch_bounds__(256) void k_scatter(
    const int* __restrict__ row, const int* __restrict__ col,
    const float* __restrict__ el, const float* __restrict__ er,
    const float* __restrict__ h, float* __restrict__ out)
{
    int e = blockIdx.x * 4 + (threadIdx.x >> 6);
    if (e >= N_EDGES) return;
    int lane = threadIdx.x & 63;
    int r = row[e], c = col[e];

    float hv = h[(size_t)c * OUT_F + lane];
    float4 elv = *reinterpret_cast<const float4*>(el + r * 4);
    float4 erv = *reinterpret_cast<const float4*>(er + c * 4);
    float s[4] = {elv.x + erv.x, elv.y + erv.y, elv.z + erv.z, elv.w + erv.w};
    float* orow = out + (size_t)r * (N_HEADS * OUT_F);
    #pragma unroll
    for (int hd = 0; hd < 4; ++hd) {
        float v = s[hd] > 0.f ? s[hd] : NEG_SLOPE * s[hd];
        float ev = expf(v);
        atomicAdd(&orow[hd * 64 + lane], ev * hv);
    }
}

// ---------------------------------------------------------------------------
// K4: out = out / max(denom[row], EPS) + b[d]   (in place)
// ---------------------------------------------------------------------------
__global__ __launch_bounds__(256) void k_final(
    const float* __restrict__ denom, const float* __restrict__ b,
    float* __restrict__ out)
{
    int i = blockIdx.x * 256 + threadIdx.x;
    if (i >= N_NODES * N_HEADS * OUT_F) return;
    int n  = i >> 8;          // / 256
    int hd = (i >> 6) & 3;
    int d  = i & 63;
    float dn = fmaxf(denom[n * 4 + hd], EPS);
    out[i] = out[i] / dn + b[d];
}

extern "C" void kernel_launch(void* const* d_in, const int* in_sizes, int n_in,
                              void* d_out, int out_size, void* d_ws, size_t ws_size,
                              hipStream_t stream)
{
    const float* x   = (const float*)d_in[0];
    const int*   ei  = (const int*)d_in[1];
    const float* W   = (const float*)d_in[2];
    const float* a_l = (const float*)d_in[3];
    const float* a_r = (const float*)d_in[4];
    const float* b   = (const float*)d_in[5];
    float* out = (float*)d_out;

    char* ws = (char*)d_ws;
    float* h     = (float*)(ws);                 // 12,800,000 B
    float* el    = (float*)(ws + 12800000);      //    800,000 B
    float* er    = (float*)(ws + 13600000);      //    800,000 B
    float* denom = (float*)(ws + 14400000);      //    800,000 B

    const int* row = ei;            // edge_index[0]
    const int* col = ei + N_EDGES;  // edge_index[1]

    hipMemsetAsync(out, 0, (size_t)N_NODES * N_HEADS * OUT_F * sizeof(float), stream);
    hipMemsetAsync(denom, 0, (size_t)N_NODES * N_HEADS * sizeof(float), stream);

    k_h_el_er<<<N_NODES / 4, 256, 0, stream>>>(x, W, a_l, a_r, h, el, er);
    k_denom<<<(N_EDGES + 255) / 256, 256, 0, stream>>>(row, col, el, er, denom);
    k_scatter<<<N_EDGES / 4, 256, 0, stream>>>(row, col, el, er, h, out);
    k_final<<<(N_NODES * N_HEADS * OUT_F + 255) / 256, 256, 0, stream>>>(denom, b, out);
}

// Round 2
// 343.284 us; speedup vs baseline: 2.6857x; 2.6857x over previous
//
#include <hip/hip_runtime.h>

#define N_NODES 50000
#define N_EDGES 800000
#define IN_F    128
#define OUT_F   64
#define N_HEADS 4
#define NEG_SLOPE 0.2f
#define EPS 1e-12f

// ---------------------------------------------------------------------------
// K1: h = x @ W  (per-node), fused el = h@a_l, er = h@a_r via wave reduction.
// Block = 256 threads = 4 nodes, one wave (64 lanes) per node, lane = out feat.
// ---------------------------------------------------------------------------
__global__ __launch_bounds__(256) void k_h_el_er(
    const float* __restrict__ x, const float* __restrict__ W,
    const float* __restrict__ a_l, const float* __restrict__ a_r,
    float* __restrict__ h, float* __restrict__ el, float* __restrict__ er)
{
    __shared__ float Wl[IN_F][OUT_F];   // 32 KB
    __shared__ float xs[4][IN_F];       // 2 KB
    const int tid = threadIdx.x;
    const int node0 = blockIdx.x * 4;

    for (int i = tid; i < IN_F * OUT_F; i += 256)
        Wl[i / OUT_F][i % OUT_F] = W[i];
    for (int i = tid; i < 4 * IN_F; i += 256) {
        int n = node0 + i / IN_F;
        xs[i / IN_F][i % IN_F] = (n < N_NODES) ? x[(size_t)n * IN_F + (i % IN_F)] : 0.f;
    }
    __syncthreads();

    const int local = tid >> 6;   // node within block == wave id
    const int d     = tid & 63;   // output feature
    const int n     = node0 + local;

    float acc = 0.f;
    #pragma unroll
    for (int k = 0; k < IN_F; ++k)
        acc += xs[local][k] * Wl[k][d];

    if (n < N_NODES) h[(size_t)n * OUT_F + d] = acc;

    #pragma unroll
    for (int hd = 0; hd < N_HEADS; ++hd) {
        float vl = acc * a_l[d * N_HEADS + hd];
        float vr = acc * a_r[d * N_HEADS + hd];
        #pragma unroll
        for (int off = 32; off > 0; off >>= 1) {
            vl += __shfl_down(vl, off);
            vr += __shfl_down(vr, off);
        }
        if (d == 0 && n < N_NODES) {
            el[n * N_HEADS + hd] = vl;
            er[n * N_HEADS + hd] = vr;
        }
    }
}

// ---------------------------------------------------------------------------
// K2: per-row in-degree count
// ---------------------------------------------------------------------------
__global__ __launch_bounds__(256) void k_count(
    const int* __restrict__ row, int* __restrict__ deg)
{
    int e = blockIdx.x * 256 + threadIdx.x;
    if (e >= N_EDGES) return;
    atomicAdd(&deg[row[e]], 1);
}

// ---------------------------------------------------------------------------
// K3: single-block exclusive scan over deg -> rowptr[N_NODES+1]
// ---------------------------------------------------------------------------
#define SCAN_T 1024
#define SCAN_CHUNK 49   // 1024*49 = 50176 >= 50000
__global__ __launch_bounds__(1024) void k_scan(
    const int* __restrict__ deg, int* __restrict__ rowptr)
{
    __shared__ int sums[SCAN_T];
    const int t = threadIdx.x;
    const int start = t * SCAN_CHUNK;
    int s = 0;
    for (int i = 0; i < SCAN_CHUNK; ++i) {
        int idx = start + i;
        s += (idx < N_NODES) ? deg[idx] : 0;
    }
    sums[t] = s;
    __syncthreads();
    // inclusive scan (Hillis-Steele)
    for (int off = 1; off < SCAN_T; off <<= 1) {
        int v = (t >= off) ? sums[t - off] : 0;
        __syncthreads();
        sums[t] += v;
        __syncthreads();
    }
    int run = (t == 0) ? 0 : sums[t - 1];   // exclusive
    for (int i = 0; i < SCAN_CHUNK; ++i) {
        int idx = start + i;
        if (idx < N_NODES) {
            rowptr[idx] = run;
            run += deg[idx];
        }
    }
    if (t == SCAN_T - 1) rowptr[N_NODES] = run;
}

// ---------------------------------------------------------------------------
// K4: scatter edges into CSR slots
// ---------------------------------------------------------------------------
__global__ __launch_bounds__(256) void k_fill(
    const int* __restrict__ row, const int* __restrict__ col,
    const int* __restrict__ rowptr, int* __restrict__ fill,
    int* __restrict__ csr_col)
{
    int e = blockIdx.x * 256 + threadIdx.x;
    if (e >= N_EDGES) return;
    int r = row[e];
    int pos = rowptr[r] + atomicAdd(&fill[r], 1);
    csr_col[pos] = col[e];
}

// ---------------------------------------------------------------------------
// K5: gather — one wave per destination node. No atomics.
// lane = output feature d; head values broadcast via shfl from lanes 0..3.
// ---------------------------------------------------------------------------
__global__ __launch_bounds__(256) void k_gather(
    const int* __restrict__ rowptr, const int* __restrict__ csr_col,
    const float* __restrict__ el, const float* __restrict__ er,
    const float* __restrict__ h, const float* __restrict__ b,
    float* __restrict__ out)
{
    int n = blockIdx.x * 4 + (threadIdx.x >> 6);
    if (n >= N_NODES) return;
    const int lane = threadIdx.x & 63;
    const int hd   = lane & 3;

    const int start = rowptr[n], end = rowptr[n + 1];
    const float el_s = el[n * 4 + hd];

    float acc0 = 0.f, acc1 = 0.f, acc2 = 0.f, acc3 = 0.f;
    float den  = 0.f;   // denom for head (lane&3), identical across 4-lane groups

    for (int j = start; j < end; ++j) {
        int c = csr_col[j];                       // wave-uniform load
        float s = el_s + er[c * 4 + hd];          // 16B segment, broadcast
        s = s > 0.f ? s : NEG_SLOPE * s;
        float e = expf(s);                        // one exp per lane
        den += e;
        float e0 = __shfl(e, 0);
        float e1 = __shfl(e, 1);
        float e2 = __shfl(e, 2);
        float e3 = __shfl(e, 3);
        float hv = h[(size_t)c * OUT_F + lane];   // 256B coalesced
        acc0 += e0 * hv;
        acc1 += e1 * hv;
        acc2 += e2 * hv;
        acc3 += e3 * hv;
    }

    float d0 = fmaxf(__shfl(den, 0), EPS);
    float d1 = fmaxf(__shfl(den, 1), EPS);
    float d2 = fmaxf(__shfl(den, 2), EPS);
    float d3 = fmaxf(__shfl(den, 3), EPS);

    float bias = b[lane];
    float* orow = out + (size_t)n * (N_HEADS * OUT_F);
    orow[0 * 64 + lane] = acc0 / d0 + bias;
    orow[1 * 64 + lane] = acc1 / d1 + bias;
    orow[2 * 64 + lane] = acc2 / d2 + bias;
    orow[3 * 64 + lane] = acc3 / d3 + bias;
}

extern "C" void kernel_launch(void* const* d_in, const int* in_sizes, int n_in,
                              void* d_out, int out_size, void* d_ws, size_t ws_size,
                              hipStream_t stream)
{
    const float* x   = (const float*)d_in[0];
    const int*   ei  = (const int*)d_in[1];
    const float* W   = (const float*)d_in[2];
    const float* a_l = (const float*)d_in[3];
    const float* a_r = (const float*)d_in[4];
    const float* b   = (const float*)d_in[5];
    float* out = (float*)d_out;

    char* ws = (char*)d_ws;
    float* h       = (float*)(ws);                  // 12,800,000 B
    float* el      = (float*)(ws + 12800000);       //    800,000 B
    float* er      = (float*)(ws + 13600000);       //    800,000 B
    int*   deg     = (int*)  (ws + 14400000);       //    200,000 B
    int*   fill    = (int*)  (ws + 14600000);       //    200,000 B
    int*   rowptr  = (int*)  (ws + 14800000);       //    200,016 B (50001 ints)
    int*   csr_col = (int*)  (ws + 15000016);       //  3,200,000 B
    // total: 18,200,016 B

    const int* row = ei;            // edge_index[0]
    const int* col = ei + N_EDGES;  // edge_index[1]

    // zero deg + fill in one memset (contiguous)
    hipMemsetAsync(deg, 0, 400000, stream);

    k_h_el_er<<<N_NODES / 4, 256, 0, stream>>>(x, W, a_l, a_r, h, el, er);
    k_count  <<<(N_EDGES + 255) / 256, 256, 0, stream>>>(row, deg);
    k_scan   <<<1, SCAN_T, 0, stream>>>(deg, rowptr);
    k_fill   <<<(N_EDGES + 255) / 256, 256, 0, stream>>>(row, col, rowptr, fill, csr_col);
    k_gather <<<N_NODES / 4, 256, 0, stream>>>(rowptr, csr_col, el, er, h, b, out);
}

// Round 3
// 295.220 us; speedup vs baseline: 3.1230x; 1.1628x over previous
//
#include <hip/hip_runtime.h>

#define N_NODES 50000
#define N_EDGES 800000
#define IN_F    128
#define OUT_F   64
#define N_HEADS 4
#define NEG_SLOPE 0.2f
#define EPS 1e-12f

// ---------------------------------------------------------------------------
// K1: h = x @ W, fused el = h@a_l, er = h@a_r.
// Block 256 = 4 waves; each wave computes 4 nodes x 64 features.
// Lane l: features d4=(l&15)*4..+3, k-slice kg=l>>4 (16 k's per lane).
// All LDS reads are b128: Wl[k][d4] rows spread evenly across banks,
// xs[node][k-chunk] is 4-address broadcast. Cross-k reduce via shfl_xor.
// ---------------------------------------------------------------------------
__global__ __launch_bounds__(256) void k_h_el_er(
    const float* __restrict__ x, const float* __restrict__ W,
    const float* __restrict__ a_l, const float* __restrict__ a_r,
    float* __restrict__ h, float* __restrict__ el, float* __restrict__ er)
{
    __shared__ float Wl[IN_F][OUT_F];   // 32 KB
    __shared__ float xs[16][IN_F];      // 8 KB
    const int tid = threadIdx.x;
    const int node0 = blockIdx.x * 16;  // 3125 blocks * 16 = 50000 exactly

    {
        const float4* Wv  = (const float4*)W;
        float4*       Wlv = (float4*)&Wl[0][0];
        #pragma unroll
        for (int i = 0; i < 8; ++i) Wlv[tid + 256 * i] = Wv[tid + 256 * i];
        const float4* xv  = (const float4*)(x + (size_t)node0 * IN_F);
        float4*       xsv = (float4*)&xs[0][0];
        #pragma unroll
        for (int i = 0; i < 2; ++i) xsv[tid + 256 * i] = xv[tid + 256 * i];
    }
    __syncthreads();

    const int wave = tid >> 6;
    const int l    = tid & 63;
    const int d4   = (l & 15) * 4;
    const int kg   = l >> 4;

    float acc[4][4] = {};
    #pragma unroll
    for (int ko = 0; ko < IN_F; ko += 16) {
        const int kb = ko + 4 * kg;
        float4 wv[4];
        #pragma unroll
        for (int i = 0; i < 4; ++i)
            wv[i] = *(const float4*)&Wl[kb + i][d4];
        #pragma unroll
        for (int n = 0; n < 4; ++n) {
            float4 xv4 = *(const float4*)&xs[wave * 4 + n][kb];
            const float xa[4] = {xv4.x, xv4.y, xv4.z, xv4.w};
            #pragma unroll
            for (int i = 0; i < 4; ++i) {
                acc[n][0] += xa[i] * wv[i].x;
                acc[n][1] += xa[i] * wv[i].y;
                acc[n][2] += xa[i] * wv[i].z;
                acc[n][3] += xa[i] * wv[i].w;
            }
        }
    }

    // butterfly-reduce across the 4 k-groups (lanes l, l^16, l^32)
    #pragma unroll
    for (int n = 0; n < 4; ++n)
        #pragma unroll
        for (int j = 0; j < 4; ++j) {
            float v = acc[n][j];
            v += __shfl_xor(v, 16);
            v += __shfl_xor(v, 32);
            acc[n][j] = v;
        }

    // write h: lanes 0..15 hold the full 64 features per node
    if (l < 16) {
        #pragma unroll
        for (int n = 0; n < 4; ++n) {
            const int node = node0 + wave * 4 + n;
            *(float4*)&h[(size_t)node * OUT_F + d4] =
                make_float4(acc[n][0], acc[n][1], acc[n][2], acc[n][3]);
        }
    }

    // el/er: per (node, head): dot 4 local feats with a, reduce over 16 lanes
    #pragma unroll
    for (int n = 0; n < 4; ++n) {
        const int node = node0 + wave * 4 + n;
        #pragma unroll
        for (int hd = 0; hd < N_HEADS; ++hd) {
            float tl = acc[n][0] * a_l[(d4 + 0) * N_HEADS + hd]
                     + acc[n][1] * a_l[(d4 + 1) * N_HEADS + hd]
                     + acc[n][2] * a_l[(d4 + 2) * N_HEADS + hd]
                     + acc[n][3] * a_l[(d4 + 3) * N_HEADS + hd];
            float tr = acc[n][0] * a_r[(d4 + 0) * N_HEADS + hd]
                     + acc[n][1] * a_r[(d4 + 1) * N_HEADS + hd]
                     + acc[n][2] * a_r[(d4 + 2) * N_HEADS + hd]
                     + acc[n][3] * a_r[(d4 + 3) * N_HEADS + hd];
            #pragma unroll
            for (int off = 1; off < 16; off <<= 1) {
                tl += __shfl_xor(tl, off);
                tr += __shfl_xor(tr, off);
            }
            if (l == 0) {
                el[node * N_HEADS + hd] = tl;
                er[node * N_HEADS + hd] = tr;
            }
        }
    }
}

// ---------------------------------------------------------------------------
// K2: per-row in-degree count
// ---------------------------------------------------------------------------
__global__ __launch_bounds__(256) void k_count(
    const int* __restrict__ row, int* __restrict__ deg)
{
    int e = blockIdx.x * 256 + threadIdx.x;
    if (e >= N_EDGES) return;
    atomicAdd(&deg[row[e]], 1);
}

// ---------------------------------------------------------------------------
// K3: single-block exclusive scan over deg -> rowptr[N_NODES+1]
// ---------------------------------------------------------------------------
#define SCAN_T 1024
#define SCAN_CHUNK 49   // 1024*49 = 50176 >= 50000
__global__ __launch_bounds__(1024) void k_scan(
    const int* __restrict__ deg, int* __restrict__ rowptr)
{
    __shared__ int sums[SCAN_T];
    const int t = threadIdx.x;
    const int start = t * SCAN_CHUNK;
    int s = 0;
    for (int i = 0; i < SCAN_CHUNK; ++i) {
        int idx = start + i;
        s += (idx < N_NODES) ? deg[idx] : 0;
    }
    sums[t] = s;
    __syncthreads();
    for (int off = 1; off < SCAN_T; off <<= 1) {
        int v = (t >= off) ? sums[t - off] : 0;
        __syncthreads();
        sums[t] += v;
        __syncthreads();
    }
    int run = (t == 0) ? 0 : sums[t - 1];
    for (int i = 0; i < SCAN_CHUNK; ++i) {
        int idx = start + i;
        if (idx < N_NODES) {
            rowptr[idx] = run;
            run += deg[idx];
        }
    }
    if (t == SCAN_T - 1) rowptr[N_NODES] = run;
}

// ---------------------------------------------------------------------------
// K4: scatter edges into CSR slots; optionally precompute exp weights
// ---------------------------------------------------------------------------
template <bool WITH_W>
__global__ __launch_bounds__(256) void k_fill(
    const int* __restrict__ row, const int* __restrict__ col,
    const float* __restrict__ el, const float* __restrict__ er,
    const int* __restrict__ rowptr, int* __restrict__ fill,
    int* __restrict__ csr_col, float4* __restrict__ csr_w)
{
    int e = blockIdx.x * 256 + threadIdx.x;
    if (e >= N_EDGES) return;
    int r = row[e], c = col[e];
    int pos = rowptr[r] + atomicAdd(&fill[r], 1);
    csr_col[pos] = c;
    if (WITH_W) {
        float4 elv = *reinterpret_cast<const float4*>(el + r * 4);
        float4 erv = *reinterpret_cast<const float4*>(er + c * 4);
        float s0 = elv.x + erv.x, s1 = elv.y + erv.y;
        float s2 = elv.z + erv.z, s3 = elv.w + erv.w;
        s0 = s0 > 0.f ? s0 : NEG_SLOPE * s0;
        s1 = s1 > 0.f ? s1 : NEG_SLOPE * s1;
        s2 = s2 > 0.f ? s2 : NEG_SLOPE * s2;
        s3 = s3 > 0.f ? s3 : NEG_SLOPE * s3;
        csr_w[pos] = make_float4(expf(s0), expf(s1), expf(s2), expf(s3));
    }
}

// ---------------------------------------------------------------------------
// K5: gather — one wave per destination node, no atomics.
// WITH_W: weights precomputed (uniform b128 load); else compute on the fly.
// Denominator accumulated redundantly per-lane (float4) -> no shuffles.
// ---------------------------------------------------------------------------
template <bool WITH_W>
__global__ __launch_bounds__(256) void k_gather(
    const int* __restrict__ rowptr, const int* __restrict__ csr_col,
    const float4* __restrict__ csr_w,
    const float* __restrict__ el, const float* __restrict__ er,
    const float* __restrict__ h, const float* __restrict__ b,
    float* __restrict__ out)
{
    int n = blockIdx.x * 4 + (threadIdx.x >> 6);
    if (n >= N_NODES) return;
    const int lane = threadIdx.x & 63;

    const int s0 = rowptr[n], s1 = rowptr[n + 1];

    float a0 = 0.f, a1 = 0.f, a2 = 0.f, a3 = 0.f;
    float d0 = 0.f, d1 = 0.f, d2 = 0.f, d3 = 0.f;

    float4 elv;
    if (!WITH_W) elv = *reinterpret_cast<const float4*>(el + n * 4);

    int j = s0;
    int c_nx = 0; float4 w_nx = make_float4(0.f, 0.f, 0.f, 0.f);
    if (j < s1) {
        c_nx = csr_col[j];
        if (WITH_W) w_nx = csr_w[j];
    }
    while (j < s1) {
        const int c = c_nx;
        float4 w = w_nx;
        const float hv = h[(size_t)c * OUT_F + lane];
        ++j;
        if (j < s1) {
            c_nx = csr_col[j];
            if (WITH_W) w_nx = csr_w[j];
        }
        if (!WITH_W) {
            float4 erv = *reinterpret_cast<const float4*>(er + c * 4);
            float s0f = elv.x + erv.x, s1f = elv.y + erv.y;
            float s2f = elv.z + erv.z, s3f = elv.w + erv.w;
            s0f = s0f > 0.f ? s0f : NEG_SLOPE * s0f;
            s1f = s1f > 0.f ? s1f : NEG_SLOPE * s1f;
            s2f = s2f > 0.f ? s2f : NEG_SLOPE * s2f;
            s3f = s3f > 0.f ? s3f : NEG_SLOPE * s3f;
            w = make_float4(expf(s0f), expf(s1f), expf(s2f), expf(s3f));
        }
        d0 += w.x; d1 += w.y; d2 += w.z; d3 += w.w;
        a0 += w.x * hv; a1 += w.y * hv; a2 += w.z * hv; a3 += w.w * hv;
    }

    const float bias = b[lane];
    float* orow = out + (size_t)n * (N_HEADS * OUT_F);
    orow[0 * 64 + lane] = a0 / fmaxf(d0, EPS) + bias;
    orow[1 * 64 + lane] = a1 / fmaxf(d1, EPS) + bias;
    orow[2 * 64 + lane] = a2 / fmaxf(d2, EPS) + bias;
    orow[3 * 64 + lane] = a3 / fmaxf(d3, EPS) + bias;
}

extern "C" void kernel_launch(void* const* d_in, const int* in_sizes, int n_in,
                              void* d_out, int out_size, void* d_ws, size_t ws_size,
                              hipStream_t stream)
{
    const float* x   = (const float*)d_in[0];
    const int*   ei  = (const int*)d_in[1];
    const float* W   = (const float*)d_in[2];
    const float* a_l = (const float*)d_in[3];
    const float* a_r = (const float*)d_in[4];
    const float* b   = (const float*)d_in[5];
    float* out = (float*)d_out;

    char* ws = (char*)d_ws;
    float*  h       = (float*) (ws);                  // 12,800,000 B
    float*  el      = (float*) (ws + 12800000);       //    800,000 B
    float*  er      = (float*) (ws + 13600000);       //    800,000 B
    int*    deg     = (int*)   (ws + 14400000);       //    200,000 B
    int*    fill    = (int*)   (ws + 14600000);       //    200,000 B
    int*    rowptr  = (int*)   (ws + 14800000);       //    200,016 B
    int*    csr_col = (int*)   (ws + 15000016);       //  3,200,000 B
    float4* csr_w   = (float4*)(ws + 18200016);       // 12,800,000 B
    const size_t NEED_W = 31000016;

    const int* row = ei;
    const int* col = ei + N_EDGES;

    hipMemsetAsync(deg, 0, 400000, stream);  // deg + fill contiguous

    k_h_el_er<<<N_NODES / 16, 256, 0, stream>>>(x, W, a_l, a_r, h, el, er);
    k_count  <<<(N_EDGES + 255) / 256, 256, 0, stream>>>(row, deg);
    k_scan   <<<1, SCAN_T, 0, stream>>>(deg, rowptr);
    if (ws_size >= NEED_W) {
        k_fill<true>   <<<(N_EDGES + 255) / 256, 256, 0, stream>>>(row, col, el, er, rowptr, fill, csr_col, csr_w);
        k_gather<true> <<<N_NODES / 4, 256, 0, stream>>>(rowptr, csr_col, csr_w, el, er, h, b, out);
    } else {
        k_fill<false>  <<<(N_EDGES + 255) / 256, 256, 0, stream>>>(row, col, el, er, rowptr, fill, csr_col, csr_w);
        k_gather<false><<<N_NODES / 4, 256, 0, stream>>>(rowptr, csr_col, csr_w, el, er, h, b, out);
    }
}

// Round 4
// 211.131 us; speedup vs baseline: 4.3668x; 1.3983x over previous
//
#include <hip/hip_runtime.h>

#define N_NODES 50000
#define N_EDGES 800000
#define IN_F    128
#define OUT_F   64
#define N_HEADS 4
#define NEG_SLOPE 0.2f
#define EPS 1e-12f
#define SB 49   // scan blocks: 49 * 1024 = 50176 >= N_NODES

// ---------------------------------------------------------------------------
// K1: h = x @ W, fused el = h@a_l, er = h@a_r.
// Block 256 = 4 waves; each wave computes 4 nodes x 64 features.
// Lane l: features d4=(l&15)*4..+3, k-slice kg=l>>4 (16 k's per lane).
// ---------------------------------------------------------------------------
__global__ __launch_bounds__(256) void k_h_el_er(
    const float* __restrict__ x, const float* __restrict__ W,
    const float* __restrict__ a_l, const float* __restrict__ a_r,
    float* __restrict__ h, float* __restrict__ el, float* __restrict__ er)
{
    __shared__ float Wl[IN_F][OUT_F];   // 32 KB
    __shared__ float xs[16][IN_F];      // 8 KB
    const int tid = threadIdx.x;
    const int node0 = blockIdx.x * 16;  // 3125 blocks * 16 = 50000 exactly

    {
        const float4* Wv  = (const float4*)W;
        float4*       Wlv = (float4*)&Wl[0][0];
        #pragma unroll
        for (int i = 0; i < 8; ++i) Wlv[tid + 256 * i] = Wv[tid + 256 * i];
        const float4* xv  = (const float4*)(x + (size_t)node0 * IN_F);
        float4*       xsv = (float4*)&xs[0][0];
        #pragma unroll
        for (int i = 0; i < 2; ++i) xsv[tid + 256 * i] = xv[tid + 256 * i];
    }
    __syncthreads();

    const int wave = tid >> 6;
    const int l    = tid & 63;
    const int d4   = (l & 15) * 4;
    const int kg   = l >> 4;

    float acc[4][4] = {};
    #pragma unroll
    for (int ko = 0; ko < IN_F; ko += 16) {
        const int kb = ko + 4 * kg;
        float4 wv[4];
        #pragma unroll
        for (int i = 0; i < 4; ++i)
            wv[i] = *(const float4*)&Wl[kb + i][d4];
        #pragma unroll
        for (int n = 0; n < 4; ++n) {
            float4 xv4 = *(const float4*)&xs[wave * 4 + n][kb];
            const float xa[4] = {xv4.x, xv4.y, xv4.z, xv4.w};
            #pragma unroll
            for (int i = 0; i < 4; ++i) {
                acc[n][0] += xa[i] * wv[i].x;
                acc[n][1] += xa[i] * wv[i].y;
                acc[n][2] += xa[i] * wv[i].z;
                acc[n][3] += xa[i] * wv[i].w;
            }
        }
    }

    #pragma unroll
    for (int n = 0; n < 4; ++n)
        #pragma unroll
        for (int j = 0; j < 4; ++j) {
            float v = acc[n][j];
            v += __shfl_xor(v, 16);
            v += __shfl_xor(v, 32);
            acc[n][j] = v;
        }

    if (l < 16) {
        #pragma unroll
        for (int n = 0; n < 4; ++n) {
            const int node = node0 + wave * 4 + n;
            *(float4*)&h[(size_t)node * OUT_F + d4] =
                make_float4(acc[n][0], acc[n][1], acc[n][2], acc[n][3]);
        }
    }

    #pragma unroll
    for (int n = 0; n < 4; ++n) {
        const int node = node0 + wave * 4 + n;
        #pragma unroll
        for (int hd = 0; hd < N_HEADS; ++hd) {
            float tl = acc[n][0] * a_l[(d4 + 0) * N_HEADS + hd]
                     + acc[n][1] * a_l[(d4 + 1) * N_HEADS + hd]
                     + acc[n][2] * a_l[(d4 + 2) * N_HEADS + hd]
                     + acc[n][3] * a_l[(d4 + 3) * N_HEADS + hd];
            float tr = acc[n][0] * a_r[(d4 + 0) * N_HEADS + hd]
                     + acc[n][1] * a_r[(d4 + 1) * N_HEADS + hd]
                     + acc[n][2] * a_r[(d4 + 2) * N_HEADS + hd]
                     + acc[n][3] * a_r[(d4 + 3) * N_HEADS + hd];
            #pragma unroll
            for (int off = 1; off < 16; off <<= 1) {
                tl += __shfl_xor(tl, off);
                tr += __shfl_xor(tr, off);
            }
            if (l == 0) {
                el[node * N_HEADS + hd] = tl;
                er[node * N_HEADS + hd] = tr;
            }
        }
    }
}

// ---------------------------------------------------------------------------
// K2: per-row in-degree count
// ---------------------------------------------------------------------------
__global__ __launch_bounds__(256) void k_count(
    const int* __restrict__ row, int* __restrict__ deg)
{
    int e = blockIdx.x * 256 + threadIdx.x;
    if (e >= N_EDGES) return;
    atomicAdd(&deg[row[e]], 1);
}

// ---------------------------------------------------------------------------
// K3a: per-block exclusive scan (1024 elems/block), emits block totals
// ---------------------------------------------------------------------------
__global__ __launch_bounds__(256) void k_scan_local(
    const int* __restrict__ deg, int* __restrict__ rowptr,
    int* __restrict__ blocksum)
{
    __shared__ int wsum[4];
    const int t = threadIdx.x;
    const int base = blockIdx.x * 1024 + t * 4;

    int4 d = make_int4(0, 0, 0, 0);
    if (base + 3 < N_NODES) d = *(const int4*)(deg + base);
    else {
        if (base + 0 < N_NODES) d.x = deg[base + 0];
        if (base + 1 < N_NODES) d.y = deg[base + 1];
        if (base + 2 < N_NODES) d.z = deg[base + 2];
        if (base + 3 < N_NODES) d.w = deg[base + 3];
    }
    const int tsum = d.x + d.y + d.z + d.w;

    const int lane = t & 63, wave = t >> 6;
    int inc = tsum;
    #pragma unroll
    for (int off = 1; off < 64; off <<= 1) {
        int v = __shfl_up(inc, off);
        if (lane >= off) inc += v;
    }
    if (lane == 63) wsum[wave] = inc;
    __syncthreads();

    int woff = 0;
    #pragma unroll
    for (int w = 0; w < 4; ++w) woff += (w < wave) ? wsum[w] : 0;

    const int ex = woff + inc - tsum;
    int4 o;
    o.x = ex; o.y = ex + d.x; o.z = o.y + d.y; o.w = o.z + d.z;
    if (base + 3 < N_NODES) *(int4*)(rowptr + base) = o;
    else {
        if (base + 0 < N_NODES) rowptr[base + 0] = o.x;
        if (base + 1 < N_NODES) rowptr[base + 1] = o.y;
        if (base + 2 < N_NODES) rowptr[base + 2] = o.z;
        if (base + 3 < N_NODES) rowptr[base + 3] = o.w;
    }
    if (t == 0) blocksum[blockIdx.x] = wsum[0] + wsum[1] + wsum[2] + wsum[3];
}

// ---------------------------------------------------------------------------
// K3b: add preceding-block offsets; block SB-1 writes rowptr[N_NODES]
// ---------------------------------------------------------------------------
__global__ __launch_bounds__(256) void k_scan_add(
    const int* __restrict__ blocksum, int* __restrict__ rowptr)
{
    const int bb = blockIdx.x;
    int off = 0;
    for (int i = 0; i < bb; ++i) off += blocksum[i];   // broadcast L2 loads

    const int t = threadIdx.x;
    if (bb == SB - 1 && t == 0) rowptr[N_NODES] = off + blocksum[SB - 1];
    if (off == 0) return;   // block 0

    const int base = bb * 1024 + t * 4;
    if (base + 3 < N_NODES) {
        int4 v = *(int4*)(rowptr + base);
        v.x += off; v.y += off; v.z += off; v.w += off;
        *(int4*)(rowptr + base) = v;
    } else {
        if (base + 0 < N_NODES) rowptr[base + 0] += off;
        if (base + 1 < N_NODES) rowptr[base + 1] += off;
        if (base + 2 < N_NODES) rowptr[base + 2] += off;
        if (base + 3 < N_NODES) rowptr[base + 3] += off;
    }
}

// ---------------------------------------------------------------------------
// K4: scatter edges into CSR slots; optionally precompute exp weights
// ---------------------------------------------------------------------------
template <bool WITH_W>
__global__ __launch_bounds__(256) void k_fill(
    const int* __restrict__ row, const int* __restrict__ col,
    const float* __restrict__ el, const float* __restrict__ er,
    const int* __restrict__ rowptr, int* __restrict__ fill,
    int* __restrict__ csr_col, float4* __restrict__ csr_w)
{
    int e = blockIdx.x * 256 + threadIdx.x;
    if (e >= N_EDGES) return;
    int r = row[e], c = col[e];
    int pos = rowptr[r] + atomicAdd(&fill[r], 1);
    csr_col[pos] = c;
    if (WITH_W) {
        float4 elv = *reinterpret_cast<const float4*>(el + r * 4);
        float4 erv = *reinterpret_cast<const float4*>(er + c * 4);
        float s0 = elv.x + erv.x, s1 = elv.y + erv.y;
        float s2 = elv.z + erv.z, s3 = elv.w + erv.w;
        s0 = s0 > 0.f ? s0 : NEG_SLOPE * s0;
        s1 = s1 > 0.f ? s1 : NEG_SLOPE * s1;
        s2 = s2 > 0.f ? s2 : NEG_SLOPE * s2;
        s3 = s3 > 0.f ? s3 : NEG_SLOPE * s3;
        csr_w[pos] = make_float4(expf(s0), expf(s1), expf(s2), expf(s3));
    }
}

// ---------------------------------------------------------------------------
// K5: gather — one wave per destination node, no atomics.
// ---------------------------------------------------------------------------
template <bool WITH_W>
__global__ __launch_bounds__(256) void k_gather(
    const int* __restrict__ rowptr, const int* __restrict__ csr_col,
    const float4* __restrict__ csr_w,
    const float* __restrict__ el, const float* __restrict__ er,
    const float* __restrict__ h, const float* __restrict__ b,
    float* __restrict__ out)
{
    int n = blockIdx.x * 4 + (threadIdx.x >> 6);
    if (n >= N_NODES) return;
    const int lane = threadIdx.x & 63;

    const int s0 = rowptr[n], s1 = rowptr[n + 1];

    float a0 = 0.f, a1 = 0.f, a2 = 0.f, a3 = 0.f;
    float d0 = 0.f, d1 = 0.f, d2 = 0.f, d3 = 0.f;

    float4 elv;
    if (!WITH_W) elv = *reinterpret_cast<const float4*>(el + n * 4);

    int j = s0;
    int c_nx = 0; float4 w_nx = make_float4(0.f, 0.f, 0.f, 0.f);
    if (j < s1) {
        c_nx = csr_col[j];
        if (WITH_W) w_nx = csr_w[j];
    }
    while (j < s1) {
        const int c = c_nx;
        float4 w = w_nx;
        const float hv = h[(size_t)c * OUT_F + lane];
        ++j;
        if (j < s1) {
            c_nx = csr_col[j];
            if (WITH_W) w_nx = csr_w[j];
        }
        if (!WITH_W) {
            float4 erv = *reinterpret_cast<const float4*>(er + c * 4);
            float s0f = elv.x + erv.x, s1f = elv.y + erv.y;
            float s2f = elv.z + erv.z, s3f = elv.w + erv.w;
            s0f = s0f > 0.f ? s0f : NEG_SLOPE * s0f;
            s1f = s1f > 0.f ? s1f : NEG_SLOPE * s1f;
            s2f = s2f > 0.f ? s2f : NEG_SLOPE * s2f;
            s3f = s3f > 0.f ? s3f : NEG_SLOPE * s3f;
            w = make_float4(expf(s0f), expf(s1f), expf(s2f), expf(s3f));
        }
        d0 += w.x; d1 += w.y; d2 += w.z; d3 += w.w;
        a0 += w.x * hv; a1 += w.y * hv; a2 += w.z * hv; a3 += w.w * hv;
    }

    const float bias = b[lane];
    float* orow = out + (size_t)n * (N_HEADS * OUT_F);
    orow[0 * 64 + lane] = a0 / fmaxf(d0, EPS) + bias;
    orow[1 * 64 + lane] = a1 / fmaxf(d1, EPS) + bias;
    orow[2 * 64 + lane] = a2 / fmaxf(d2, EPS) + bias;
    orow[3 * 64 + lane] = a3 / fmaxf(d3, EPS) + bias;
}

extern "C" void kernel_launch(void* const* d_in, const int* in_sizes, int n_in,
                              void* d_out, int out_size, void* d_ws, size_t ws_size,
                              hipStream_t stream)
{
    const float* x   = (const float*)d_in[0];
    const int*   ei  = (const int*)d_in[1];
    const float* W   = (const float*)d_in[2];
    const float* a_l = (const float*)d_in[3];
    const float* a_r = (const float*)d_in[4];
    const float* b   = (const float*)d_in[5];
    float* out = (float*)d_out;

    char* ws = (char*)d_ws;
    float*  h        = (float*) (ws);                  // 12,800,000 B
    float*  el       = (float*) (ws + 12800000);       //    800,000 B
    float*  er       = (float*) (ws + 13600000);       //    800,000 B
    int*    deg      = (int*)   (ws + 14400000);       //    200,000 B
    int*    fill     = (int*)   (ws + 14600000);       //    200,000 B
    int*    rowptr   = (int*)   (ws + 14800000);       //    200,016 B
    int*    blocksum = (int*)   (ws + 15000016);       //        256 B
    int*    csr_col  = (int*)   (ws + 15000272);       //  3,200,000 B
    float4* csr_w    = (float4*)(ws + 18200272);       // 12,800,000 B
    const size_t NEED_W = 31000272;

    const int* row = ei;
    const int* col = ei + N_EDGES;

    hipMemsetAsync(deg, 0, 400000, stream);  // deg + fill contiguous

    k_h_el_er   <<<N_NODES / 16, 256, 0, stream>>>(x, W, a_l, a_r, h, el, er);
    k_count     <<<(N_EDGES + 255) / 256, 256, 0, stream>>>(row, deg);
    k_scan_local<<<SB, 256, 0, stream>>>(deg, rowptr, blocksum);
    k_scan_add  <<<SB, 256, 0, stream>>>(blocksum, rowptr);
    if (ws_size >= NEED_W) {
        k_fill<true>   <<<(N_EDGES + 255) / 256, 256, 0, stream>>>(row, col, el, er, rowptr, fill, csr_col, csr_w);
        k_gather<true> <<<N_NODES / 4, 256, 0, stream>>>(rowptr, csr_col, csr_w, el, er, h, b, out);
    } else {
        k_fill<false>  <<<(N_EDGES + 255) / 256, 256, 0, stream>>>(row, col, el, er, rowptr, fill, csr_col, csr_w);
        k_gather<false><<<N_NODES / 4, 256, 0, stream>>>(rowptr, csr_col, csr_w, el, er, h, b, out);
    }
}